// Round 11
// baseline (221.294 us; speedup 1.0000x reference)
//
#include <hip/hip_runtime.h>
#include <stdint.h>

// MHA forward. Inputs fp32, OUTPUT fp32, compute bf16-MFMA with fp32 acc.
// ws (bf16): qkv[4096][3072] | attn[4096][1024] | xb | wqkvb | wob = 48 MiB.

#define DIM 1024
#define SEQ 2048
#define BATCH 2
#define ROWS 4096
#define RSTRIDE 3072  // qkv row stride (ushorts)

typedef __bf16 bf16_t;
typedef bf16_t bf16x4 __attribute__((ext_vector_type(4)));
typedef bf16_t bf16x8 __attribute__((ext_vector_type(8)));
typedef float f32x4 __attribute__((ext_vector_type(4)));
typedef short s16x4 __attribute__((ext_vector_type(4)));

__device__ __forceinline__ ushort f2bf(float f) {
    uint32_t u;
    __builtin_memcpy(&u, &f, 4);
    uint32_t r = (u + 0x7fffu + ((u >> 16) & 1u)) >> 16;  // RNE
    return (ushort)r;
}

__device__ __forceinline__ void store_out(ushort* p, float v) { *p = f2bf(v); }
__device__ __forceinline__ void store_out(float* p, float v) { *p = v; }

__device__ __forceinline__ void gl_lds16(const void* g, void* l) {
    __builtin_amdgcn_global_load_lds(
        (const __attribute__((address_space(1))) void*)g,
        (__attribute__((address_space(3))) void*)l, 16, 0, 0);
}

// Fused bf16 conversion of x | w_qkv | w_o into the contiguous ws region
// xb|wqkvb|wob. Region boundaries (4M, 7M elems) are multiples of the
// per-block span (2048), so the branch is block-uniform.
__global__ __launch_bounds__(256) void cvt3_kernel(
    const float* __restrict__ x, const float* __restrict__ wq,
    const float* __restrict__ wo, ushort* __restrict__ dst) {
    size_t i = ((size_t)blockIdx.x * 256 + threadIdx.x) * 8;
    const size_t n_x = (size_t)ROWS * DIM;            // 4,194,304
    const size_t n_wq = (size_t)3 * DIM * DIM;        // 3,145,728
    const float* src;
    size_t off;
    if (i < n_x) {
        src = x; off = i;
    } else if (i < n_x + n_wq) {
        src = wq; off = i - n_x;
    } else {
        src = wo; off = i - n_x - n_wq;
    }
    float4 a = *(const float4*)(src + off);
    float4 b = *(const float4*)(src + off + 4);
    uint4 u;
    u.x = (uint)f2bf(a.x) | ((uint)f2bf(a.y) << 16);
    u.y = (uint)f2bf(a.z) | ((uint)f2bf(a.w) << 16);
    u.z = (uint)f2bf(b.x) | ((uint)f2bf(b.y) << 16);
    u.w = (uint)f2bf(b.z) | ((uint)f2bf(b.w) << 16);
    *(uint4*)(dst + i) = u;
}

// XCD-chunked bijective block-id swizzle (T1): work = (lin%8)*(nwg/8)+lin/8.
// Each XCD gets a contiguous chunk of work-ids. Requires nwg%8==0.
// Used ONLY by flash (measured: FETCH 69.7->12.3 MB, -4 us).
__device__ __forceinline__ int xcd_swz(int lin, int nwg) {
    return (lin & 7) * (nwg >> 3) + (lin >> 3);
}

// C[M,N] = A[M,K] @ B[N,K]^T (+bias), bf16 in, fp32 acc. 256 threads,
// 128xBN tile, 4 waves (2x2 of 64x(BN/2)), BK=64.
// LDS-byte arithmetic (round 11): the previous both-operands-in-LDS loop
// moved 96 KB/block/K-step through the 128 B/cy LDS pipe = ~82% of the
// step wall at 3 blocks/CU -> LDS-BW-bound. B (weights, L2-resident) is
// therefore read DIRECTLY from global in MFMA fragment layout (16 rows x
// 64 B coalesced segments per instr), like flash reads Q. This halves LDS
// traffic (48 KB/step: A stage 16 + A frag reads 32) and drops LDS to
// 16 KB. The 8 B-loads issue between the barriers (no LDS dependency), so
// their L2 latency drains with the A-DMA vmcnt(0) at no serial cost.
// A stays LDS-staged (A-direct would add 384 MB of L2 reads, no win).
// XOR-swizzled A staging: lane sources global chunk (c8^rd) so LDS chunk c
// of row R holds global chunk c^(R&7) -> ds_read_b128 frags 2 lanes/bank.
template <typename OutT, int BN>
__global__ __launch_bounds__(256) void gemm_bt_kernel(
    const ushort* __restrict__ A, const ushort* __restrict__ B,
    const float* __restrict__ bias, OutT* __restrict__ C,
    int M, int N, int K) {
    constexpr int JN = BN / 32;  // MFMA col-tiles per wave: 4 or 2
    __shared__ __align__(16) ushort sA[128 * 64];  // 16 KB (A only)

    const int tid = threadIdx.x;
    const int lane = tid & 63, w = tid >> 6;
    const int quad = lane >> 4, l15 = lane & 15;
    const int wm = (w >> 1) * 64, wn = (w & 1) * (BN / 2);
    const int bm = blockIdx.y, bn = blockIdx.x;

    f32x4 acc[4][JN];
#pragma unroll
    for (int i = 0; i < 4; i++)
#pragma unroll
        for (int j = 0; j < JN; j++) acc[i][j] = (f32x4){0.f, 0.f, 0.f, 0.f};

    const ushort* Abase = A + (size_t)(bm * 128) * K;
    const ushort* Bbase = B + (size_t)(bn * BN) * K;
    const int rd = lane >> 3, c8 = lane & 7;  // 8 rows x 8 chunks per DMA instr
    const int sw = l15 & 7;                   // read-side unswizzle

    // per-thread B fragment row pointers (row = bn*BN + wn + j*16 + l15)
    const ushort* Brow[JN];
#pragma unroll
    for (int j = 0; j < JN; j++)
        Brow[j] = Bbase + (size_t)(wn + j * 16 + l15) * K + quad * 8;

    for (int kk = 0; kk < K; kk += 64) {
        __syncthreads();  // prev step's sA reads done
#pragma unroll
        for (int t = 0; t < 4; t++) {
            int row = w * 32 + t * 8;
            gl_lds16(Abase + (size_t)(row + rd) * K + kk + ((c8 ^ rd) * 8),
                     sA + row * 64);
        }
        // B fragments straight from global/L2 (no LDS round-trip); issued
        // here so their latency drains together with the staging vmcnt(0).
        bf16x8 bfr[2][JN];
#pragma unroll
        for (int kh = 0; kh < 2; kh++)
#pragma unroll
            for (int j = 0; j < JN; j++)
                bfr[kh][j] = *(const bf16x8*)(Brow[j] + kk + kh * 32);
        __syncthreads();  // sA visible (and B frags arrived)

#pragma unroll
        for (int kh = 0; kh < 2; kh++) {
            bf16x8 af[4];
#pragma unroll
            for (int i = 0; i < 4; i++)
                af[i] = *(const bf16x8*)((const bf16_t*)sA +
                        (wm + i * 16 + l15) * 64 + (((kh * 4 + quad) ^ sw) * 8));
#pragma unroll
            for (int i = 0; i < 4; i++)
#pragma unroll
                for (int j = 0; j < JN; j++)
                    acc[i][j] = __builtin_amdgcn_mfma_f32_16x16x32_bf16(
                        af[i], bfr[kh][j], acc[i][j], 0, 0, 0);
        }
    }

#pragma unroll
    for (int i = 0; i < 4; i++)
#pragma unroll
        for (int j = 0; j < JN; j++) {
            int col = bn * BN + wn + j * 16 + l15;
            float bv = bias ? bias[col] : 0.f;
#pragma unroll
            for (int r = 0; r < 4; r++) {
                int row = bm * 128 + wm + i * 16 + quad * 4 + r;
                store_out(&C[(size_t)row * N + col], acc[i][j][r] + bv);
            }
        }
}

// Flash attention, no-max softmax. 128 queries/block, 512 thr = 8 waves;
// wave w owns q-rows w*16..+15. K-chunk = 128 keys. Grid 512 = 2 blocks/CU.
// SWAPPED QK^T: z = mfma(K, Q) gives lane l15 all of S[q=l15][k] in the
// A-fragment layout of v_mfma_f32_16x16x16bf16_1k, so P feeds PV straight
// from registers (no sP LDS round-trip). V reads are ds_read_b64 (chunk-
// swizzled, conflict-free). Single-buffered (explicit dbuf measured -5%,
// round 7). XCD-chunked blockIdx swizzle: the 16 q-blocks sharing one
// (b,h)'s 1 MB K/V land on the same XCD (measured: FETCH 69.7 -> 12.3 MB,
// dur 60.6 -> 56.5 us).
// LDS: sK[128][64] + sVt[64][128] = 32 KB.
__global__ __launch_bounds__(512, 4) void flash_attn_kernel(
    const ushort* __restrict__ qkv, ushort* __restrict__ out) {
    __shared__ __align__(16) ushort sK[128 * 64];   // 16 KB, swizzled chunks
    __shared__ __align__(16) ushort sVt[64 * 128];  // 16 KB, swizzled chunks

    const int tid = threadIdx.x;
    const int lane = tid & 63, w = tid >> 6;        // w 0..7
    const int quad = lane >> 4, l15 = lane & 15;
    const int sw = l15 & 7;                         // read-side swizzle key
    const int qh = quad >> 1, q1 = quad & 1;        // V b64 sub-chunk coords
    const int lin = blockIdx.y * gridDim.x + blockIdx.x;  // grid 16 x 32
    const int swzb = xcd_swz(lin, 512);             // 64 work-ids per XCD
    const int bh = swzb >> 4, b = bh >> 4, h = bh & 15;
    const int q0 = (swzb & 15) * 128;
    const ushort* qkvb = qkv + (size_t)b * SEQ * RSTRIDE + h * 64;

    // Q fragments straight from global (L2-resident; once per block)
    const ushort* qrow = qkvb + (size_t)(q0 + w * 16 + l15) * RSTRIDE;
    const bf16x8 aq0 = *(const bf16x8*)(qrow + quad * 8);
    const bf16x8 aq1 = *(const bf16x8*)(qrow + 32 + quad * 8);

    // staging coords: K rows krow,krow+64 x 16B chunk; V keypair x d-octet
    const int krow = tid >> 3, kc8 = tid & 7;
    const int kdst = krow * 64 + ((kc8 ^ (krow & 7)) * 8);  // swizzled dest
    const int vrp = tid & 63, vc = tid >> 6;   // vc == w (d-octet per wave)
    const int vch = vrp >> 2, vlo = vrp & 3;   // key-chunk / dword-in-chunk

    uint4 kreg0, kreg1, va, vb;
    {
        const ushort* kp0 = qkvb + (size_t)krow * RSTRIDE + DIM + kc8 * 8;
        kreg0 = *(const uint4*)kp0;
        kreg1 = *(const uint4*)(kp0 + (size_t)64 * RSTRIDE);
        const ushort* v0 = qkvb + (size_t)(2 * vrp) * RSTRIDE + 2 * DIM + vc * 8;
        va = *(const uint4*)v0;
        vb = *(const uint4*)(v0 + RSTRIDE);
    }

    f32x4 l_acc = (f32x4){0.f, 0.f, 0.f, 0.f};
    f32x4 o[4];
#pragma unroll
    for (int j = 0; j < 4; j++) o[j] = (f32x4){0.f, 0.f, 0.f, 0.f};

    s16x4 vones;  // bf16 1.0 x4 as raw shorts
#pragma unroll
    for (int e = 0; e < 4; e++) vones[e] = (short)0x3F80;

    const float c_exp = 0.04508422f;  // DIM^-0.5 * log2(e)

    uint* vt32 = (uint*)sVt;  // row stride 64 dwords
    for (int kb = 0; kb < SEQ; kb += 128) {
        // staged regs -> LDS (write-side swizzle: chunk ^ (row&7))
        *(uint4*)(sK + kdst) = kreg0;
        *(uint4*)(sK + 64 * 64 + kdst) = kreg1;  // row+64: same swizzle key
        {
            int base = (vc * 8) * 64 + vlo;
            vt32[base + 0 * 64 + ((vch ^ 0) << 2)] = (va.x & 0xffffu) | (vb.x << 16);
            vt32[base + 1 * 64 + ((vch ^ 1) << 2)] = (va.x >> 16) | (vb.x & 0xffff0000u);
            vt32[base + 2 * 64 + ((vch ^ 2) << 2)] = (va.y & 0xffffu) | (vb.y << 16);
            vt32[base + 3 * 64 + ((vch ^ 3) << 2)] = (va.y >> 16) | (vb.y & 0xffff0000u);
            vt32[base + 4 * 64 + ((vch ^ 4) << 2)] = (va.z & 0xffffu) | (vb.z << 16);
            vt32[base + 5 * 64 + ((vch ^ 5) << 2)] = (va.z >> 16) | (vb.z & 0xffff0000u);
            vt32[base + 6 * 64 + ((vch ^ 6) << 2)] = (va.w & 0xffffu) | (vb.w << 16);
            vt32[base + 7 * 64 + ((vch ^ 7) << 2)] = (va.w >> 16) | (vb.w & 0xffff0000u);
        }
        __syncthreads();

        // prefetch next chunk (clamped on last iter; values unused)
        int nkb = (kb + 128 < SEQ) ? kb + 128 : kb;
        {
            const ushort* kp0 = qkvb + (size_t)(nkb + krow) * RSTRIDE + DIM + kc8 * 8;
            kreg0 = *(const uint4*)kp0;
            kreg1 = *(const uint4*)(kp0 + (size_t)64 * RSTRIDE);
            const ushort* v0 =
                qkvb + (size_t)(nkb + 2 * vrp) * RSTRIDE + 2 * DIM + vc * 8;
            va = *(const uint4*)v0;
            vb = *(const uint4*)(v0 + RSTRIDE);
        }

        // S^T = K @ Q^T for 8 key tiles: lane l15 = q-row, reg r = key
        // (unscaled; scale folded into exp2)
        f32x4 s[8];
#pragma unroll
        for (int j = 0; j < 8; j++) {
            const ushort* kp = sK + (j * 16 + l15) * 64;
            bf16x8 bk0 = *(const bf16x8*)(kp + ((quad ^ sw) * 8));
            bf16x8 bk1 = *(const bf16x8*)(kp + (((4 | quad) ^ sw) * 8));
            f32x4 z = (f32x4){0.f, 0.f, 0.f, 0.f};
            __builtin_amdgcn_s_setprio(1);
            z = __builtin_amdgcn_mfma_f32_16x16x32_bf16(bk0, aq0, z, 0, 0, 0);
            z = __builtin_amdgcn_mfma_f32_16x16x32_bf16(bk1, aq1, z, 0, 0, 0);
            __builtin_amdgcn_s_setprio(0);
            s[j] = z;
        }

        // exp in-register, pack to bf16x4 A-fragments (k-order = reg order)
        s16x4 pa[8];
#pragma unroll
        for (int j = 0; j < 8; j++) {
            bf16x4 t;
#pragma unroll
            for (int r = 0; r < 4; r++)
                t[r] = (bf16_t)__builtin_amdgcn_exp2f(s[j][r] * c_exp);
            pa[j] = __builtin_bit_cast(s16x4, t);
        }

        // l_acc: row-sum of P via ones-MFMA (output row=q matches o layout)
        __builtin_amdgcn_s_setprio(1);
#pragma unroll
        for (int j = 0; j < 8; j++)
            l_acc = __builtin_amdgcn_mfma_f32_16x16x16bf16_1k(
                pa[j], vones, l_acc, 0, 0, 0);
        __builtin_amdgcn_s_setprio(0);

        // PV: o[jd] += P_tile_j @ V^T fragment, 16x16x16 per key tile
#pragma unroll
        for (int jd = 0; jd < 4; jd++) {
            const bf16_t* vp = (const bf16_t*)sVt + (jd * 16 + l15) * 128;
            __builtin_amdgcn_s_setprio(1);
#pragma unroll
            for (int j = 0; j < 8; j++) {
                int ch = 2 * j + qh;  // 16B chunk holding k = j*16 + quad*4
                bf16x4 bv = *(const bf16x4*)(vp + ((ch ^ sw) * 8 + q1 * 4));
                o[jd] = __builtin_amdgcn_mfma_f32_16x16x16bf16_1k(
                    pa[j], __builtin_bit_cast(s16x4, bv), o[jd], 0, 0, 0);
            }
            __builtin_amdgcn_s_setprio(0);
        }
        __syncthreads();  // all reads of sK/sVt done before next overwrite
    }

    // normalize, write attn [4096][1024] bf16
#pragma unroll
    for (int r = 0; r < 4; r++) {
        float inv = 1.f / l_acc[r];
        int qrow_i = q0 + w * 16 + quad * 4 + r;
#pragma unroll
        for (int j = 0; j < 4; j++) {
            out[(size_t)(b * SEQ + qrow_i) * DIM + h * 64 + j * 16 + l15] =
                f2bf(o[j][r] * inv);
        }
    }
}

extern "C" void kernel_launch(void* const* d_in, const int* in_sizes, int n_in,
                              void* d_out, int out_size, void* d_ws, size_t ws_size,
                              hipStream_t stream) {
    const float* x = (const float*)d_in[0];
    const float* w_qkv = (const float*)d_in[1];
    const float* w_o = (const float*)d_in[2];
    const float* b_o = (const float*)d_in[3];
    float* out = (float*)d_out;

    ushort* qkv = (ushort*)d_ws;                       // [4096][3072]
    ushort* attn = qkv + (size_t)ROWS * 3 * DIM;       // [4096][1024]
    ushort* xb = attn + (size_t)ROWS * DIM;            // [4096][1024]
    ushort* wqkvb = xb + (size_t)ROWS * DIM;           // [3072][1024]
    ushort* wob = wqkvb + (size_t)3 * DIM * DIM;       // [1024][1024]

    dim3 blk(256);
    // one fused conversion pass over x|w_qkv|w_o -> contiguous xb|wqkvb|wob
    cvt3_kernel<<<(ROWS * DIM + 3 * DIM * DIM + DIM * DIM) / 2048, blk, 0,
                  stream>>>(x, w_qkv, w_o, xb);

    gemm_bt_kernel<ushort, 128>
        <<<dim3(3 * DIM / 128, ROWS / 128), blk, 0, stream>>>(
            xb, wqkvb, nullptr, qkv, ROWS, 3 * DIM, DIM);
    flash_attn_kernel<<<dim3(SEQ / 128, BATCH * 16), dim3(512), 0, stream>>>(qkv, attn);
    gemm_bt_kernel<float, 64>
        <<<dim3(DIM / 64, ROWS / 128), blk, 0, stream>>>(
            attn, wob, b_o, out, ROWS, DIM, DIM);
}

// Round 12
// 177.865 us; speedup vs baseline: 1.2442x; 1.2442x over previous
//
#include <hip/hip_runtime.h>
#include <stdint.h>

// MHA forward. Inputs fp32, OUTPUT fp32, compute bf16-MFMA with fp32 acc.
// ws (bf16): qkv[4096][3072] | attn[4096][1024] | xb | wqkvb | wob = 48 MiB.

#define DIM 1024
#define SEQ 2048
#define BATCH 2
#define ROWS 4096
#define RSTRIDE 3072  // qkv row stride (ushorts)

typedef __bf16 bf16_t;
typedef bf16_t bf16x4 __attribute__((ext_vector_type(4)));
typedef bf16_t bf16x8 __attribute__((ext_vector_type(8)));
typedef float f32x4 __attribute__((ext_vector_type(4)));
typedef short s16x4 __attribute__((ext_vector_type(4)));

__device__ __forceinline__ ushort f2bf(float f) {
    uint32_t u;
    __builtin_memcpy(&u, &f, 4);
    uint32_t r = (u + 0x7fffu + ((u >> 16) & 1u)) >> 16;  // RNE
    return (ushort)r;
}

__device__ __forceinline__ void store_out(ushort* p, float v) { *p = f2bf(v); }
__device__ __forceinline__ void store_out(float* p, float v) { *p = v; }

__device__ __forceinline__ void gl_lds16(const void* g, void* l) {
    __builtin_amdgcn_global_load_lds(
        (const __attribute__((address_space(1))) void*)g,
        (__attribute__((address_space(3))) void*)l, 16, 0, 0);
}

// Fused bf16 conversion of x | w_qkv | w_o into the contiguous ws region
// xb|wqkvb|wob. Region boundaries (4M, 7M elems) are multiples of the
// per-block span (2048), so the branch is block-uniform.
__global__ __launch_bounds__(256) void cvt3_kernel(
    const float* __restrict__ x, const float* __restrict__ wq,
    const float* __restrict__ wo, ushort* __restrict__ dst) {
    size_t i = ((size_t)blockIdx.x * 256 + threadIdx.x) * 8;
    const size_t n_x = (size_t)ROWS * DIM;            // 4,194,304
    const size_t n_wq = (size_t)3 * DIM * DIM;        // 3,145,728
    const float* src;
    size_t off;
    if (i < n_x) {
        src = x; off = i;
    } else if (i < n_x + n_wq) {
        src = wq; off = i - n_x;
    } else {
        src = wo; off = i - n_x - n_wq;
    }
    float4 a = *(const float4*)(src + off);
    float4 b = *(const float4*)(src + off + 4);
    uint4 u;
    u.x = (uint)f2bf(a.x) | ((uint)f2bf(a.y) << 16);
    u.y = (uint)f2bf(a.z) | ((uint)f2bf(a.w) << 16);
    u.z = (uint)f2bf(b.x) | ((uint)f2bf(b.y) << 16);
    u.w = (uint)f2bf(b.z) | ((uint)f2bf(b.w) << 16);
    *(uint4*)(dst + i) = u;
}

// XCD-chunked bijective block-id swizzle (T1): work = (lin%8)*(nwg/8)+lin/8.
// Each XCD gets a contiguous chunk of work-ids. Requires nwg%8==0.
// Flash: measured FETCH 69.7->12.3 MB, -4 us (round 9).
// GEMMs (round 12, isolated): consecutive work-ids share the A row-panel
// (same bm); chunking pins each A panel to ONE XCD's L2 instead of all 8.
// Round 9's GEMM regression was the dbuf occupancy drop, not the swizzle --
// this round isolates the swizzle at zero structural change.
__device__ __forceinline__ int xcd_swz(int lin, int nwg) {
    return (lin & 7) * (nwg >> 3) + (lin >> 3);
}

// C[M,N] = A[M,K] @ B[N,K]^T (+bias), bf16 in, fp32 acc. 256 threads,
// 128xBN tile, 4 waves (2x2 of 64x(BN/2)), BK=64, single-buffered LDS.
// BN=128 for the qkv GEMM (768 blocks = 3/CU). BN=64 for the output GEMM
// (512 blocks = 2/CU). Both operands LDS-staged via global_load_lds
// (B-direct-from-L2 measured 77 us on GEMM1 -- HBM re-fetch latency
// exposed at every K-step barrier; round 11).
// XOR-swizzled DMA staging: lane sources global chunk (c8^rd) so LDS position
// c of row R holds global chunk c^(R&7) -> ds_read_b128 frags hit 2 lanes/bank
// (conflict-free) while global_load_lds keeps its contiguous dest.
template <typename OutT, int BN>
__global__ __launch_bounds__(256) void gemm_bt_kernel(
    const ushort* __restrict__ A, const ushort* __restrict__ B,
    const float* __restrict__ bias, OutT* __restrict__ C,
    int M, int N, int K) {
    constexpr int JN = BN / 32;  // MFMA col-tiles per wave: 4 or 2
    __shared__ __align__(16) ushort sA[128 * 64];  // 16 KB
    __shared__ __align__(16) ushort sB[BN * 64];   // 16 or 8 KB

    const int tid = threadIdx.x;
    const int lane = tid & 63, w = tid >> 6;
    const int quad = lane >> 4, l15 = lane & 15;
    const int wm = (w >> 1) * 64, wn = (w & 1) * (BN / 2);
    const int lin = blockIdx.y * gridDim.x + blockIdx.x;
    const int swz = xcd_swz(lin, gridDim.x * gridDim.y);
    const int bm = swz / gridDim.x, bn = swz % gridDim.x;

    f32x4 acc[4][JN];
#pragma unroll
    for (int i = 0; i < 4; i++)
#pragma unroll
        for (int j = 0; j < JN; j++) acc[i][j] = (f32x4){0.f, 0.f, 0.f, 0.f};

    const ushort* Abase = A + (size_t)(bm * 128) * K;
    const ushort* Bbase = B + (size_t)(bn * BN) * K;
    const int rd = lane >> 3, c8 = lane & 7;  // 8 rows x 8 chunks per DMA instr
    const int sw = l15 & 7;                   // read-side unswizzle

    for (int kk = 0; kk < K; kk += 64) {
        __syncthreads();
#pragma unroll
        for (int t = 0; t < 4; t++) {
            int row = w * 32 + t * 8;
            gl_lds16(Abase + (size_t)(row + rd) * K + kk + ((c8 ^ rd) * 8),
                     sA + row * 64);
        }
#pragma unroll
        for (int t = 0; t < BN / 32; t++) {
            int row = w * 8 + t * 32;  // 8-row aligned; 4 waves x BN/32 covers BN
            gl_lds16(Bbase + (size_t)(row + rd) * K + kk + ((c8 ^ rd) * 8),
                     sB + row * 64);
        }
        __syncthreads();

#pragma unroll
        for (int kh = 0; kh < 2; kh++) {
            bf16x8 af[4], bfr[JN];
#pragma unroll
            for (int i = 0; i < 4; i++)
                af[i] = *(const bf16x8*)((const bf16_t*)sA +
                        (wm + i * 16 + l15) * 64 + (((kh * 4 + quad) ^ sw) * 8));
#pragma unroll
            for (int j = 0; j < JN; j++)
                bfr[j] = *(const bf16x8*)((const bf16_t*)sB +
                        (wn + j * 16 + l15) * 64 + (((kh * 4 + quad) ^ sw) * 8));
#pragma unroll
            for (int i = 0; i < 4; i++)
#pragma unroll
                for (int j = 0; j < JN; j++)
                    acc[i][j] = __builtin_amdgcn_mfma_f32_16x16x32_bf16(
                        af[i], bfr[j], acc[i][j], 0, 0, 0);
        }
    }

#pragma unroll
    for (int i = 0; i < 4; i++)
#pragma unroll
        for (int j = 0; j < JN; j++) {
            int col = bn * BN + wn + j * 16 + l15;
            float bv = bias ? bias[col] : 0.f;
#pragma unroll
            for (int r = 0; r < 4; r++) {
                int row = bm * 128 + wm + i * 16 + quad * 4 + r;
                store_out(&C[(size_t)row * N + col], acc[i][j][r] + bv);
            }
        }
}

// Flash attention, no-max softmax. 128 queries/block, 512 thr = 8 waves;
// wave w owns q-rows w*16..+15. K-chunk = 128 keys. Grid 512 = 2 blocks/CU.
// SWAPPED QK^T: z = mfma(K, Q) gives lane l15 all of S[q=l15][k] in the
// A-fragment layout of v_mfma_f32_16x16x16bf16_1k, so P feeds PV straight
// from registers (no sP LDS round-trip). V reads are ds_read_b64 (chunk-
// swizzled, conflict-free). Single-buffered (explicit dbuf measured -5%,
// round 7). XCD-chunked blockIdx swizzle: the 16 q-blocks sharing one
// (b,h)'s 1 MB K/V land on the same XCD (measured: FETCH 69.7 -> 12.3 MB,
// dur 60.6 -> 56.5 us).
// LDS: sK[128][64] + sVt[64][128] = 32 KB.
__global__ __launch_bounds__(512, 4) void flash_attn_kernel(
    const ushort* __restrict__ qkv, ushort* __restrict__ out) {
    __shared__ __align__(16) ushort sK[128 * 64];   // 16 KB, swizzled chunks
    __shared__ __align__(16) ushort sVt[64 * 128];  // 16 KB, swizzled chunks

    const int tid = threadIdx.x;
    const int lane = tid & 63, w = tid >> 6;        // w 0..7
    const int quad = lane >> 4, l15 = lane & 15;
    const int sw = l15 & 7;                         // read-side swizzle key
    const int qh = quad >> 1, q1 = quad & 1;        // V b64 sub-chunk coords
    const int lin = blockIdx.y * gridDim.x + blockIdx.x;  // grid 16 x 32
    const int swzb = xcd_swz(lin, 512);             // 64 work-ids per XCD
    const int bh = swzb >> 4, b = bh >> 4, h = bh & 15;
    const int q0 = (swzb & 15) * 128;
    const ushort* qkvb = qkv + (size_t)b * SEQ * RSTRIDE + h * 64;

    // Q fragments straight from global (L2-resident; once per block)
    const ushort* qrow = qkvb + (size_t)(q0 + w * 16 + l15) * RSTRIDE;
    const bf16x8 aq0 = *(const bf16x8*)(qrow + quad * 8);
    const bf16x8 aq1 = *(const bf16x8*)(qrow + 32 + quad * 8);

    // staging coords: K rows krow,krow+64 x 16B chunk; V keypair x d-octet
    const int krow = tid >> 3, kc8 = tid & 7;
    const int kdst = krow * 64 + ((kc8 ^ (krow & 7)) * 8);  // swizzled dest
    const int vrp = tid & 63, vc = tid >> 6;   // vc == w (d-octet per wave)
    const int vch = vrp >> 2, vlo = vrp & 3;   // key-chunk / dword-in-chunk

    uint4 kreg0, kreg1, va, vb;
    {
        const ushort* kp0 = qkvb + (size_t)krow * RSTRIDE + DIM + kc8 * 8;
        kreg0 = *(const uint4*)kp0;
        kreg1 = *(const uint4*)(kp0 + (size_t)64 * RSTRIDE);
        const ushort* v0 = qkvb + (size_t)(2 * vrp) * RSTRIDE + 2 * DIM + vc * 8;
        va = *(const uint4*)v0;
        vb = *(const uint4*)(v0 + RSTRIDE);
    }

    f32x4 l_acc = (f32x4){0.f, 0.f, 0.f, 0.f};
    f32x4 o[4];
#pragma unroll
    for (int j = 0; j < 4; j++) o[j] = (f32x4){0.f, 0.f, 0.f, 0.f};

    s16x4 vones;  // bf16 1.0 x4 as raw shorts
#pragma unroll
    for (int e = 0; e < 4; e++) vones[e] = (short)0x3F80;

    const float c_exp = 0.04508422f;  // DIM^-0.5 * log2(e)

    uint* vt32 = (uint*)sVt;  // row stride 64 dwords
    for (int kb = 0; kb < SEQ; kb += 128) {
        // staged regs -> LDS (write-side swizzle: chunk ^ (row&7))
        *(uint4*)(sK + kdst) = kreg0;
        *(uint4*)(sK + 64 * 64 + kdst) = kreg1;  // row+64: same swizzle key
        {
            int base = (vc * 8) * 64 + vlo;
            vt32[base + 0 * 64 + ((vch ^ 0) << 2)] = (va.x & 0xffffu) | (vb.x << 16);
            vt32[base + 1 * 64 + ((vch ^ 1) << 2)] = (va.x >> 16) | (vb.x & 0xffff0000u);
            vt32[base + 2 * 64 + ((vch ^ 2) << 2)] = (va.y & 0xffffu) | (vb.y << 16);
            vt32[base + 3 * 64 + ((vch ^ 3) << 2)] = (va.y >> 16) | (vb.y & 0xffff0000u);
            vt32[base + 4 * 64 + ((vch ^ 4) << 2)] = (va.z & 0xffffu) | (vb.z << 16);
            vt32[base + 5 * 64 + ((vch ^ 5) << 2)] = (va.z >> 16) | (vb.z & 0xffff0000u);
            vt32[base + 6 * 64 + ((vch ^ 6) << 2)] = (va.w & 0xffffu) | (vb.w << 16);
            vt32[base + 7 * 64 + ((vch ^ 7) << 2)] = (va.w >> 16) | (vb.w & 0xffff0000u);
        }
        __syncthreads();

        // prefetch next chunk (clamped on last iter; values unused)
        int nkb = (kb + 128 < SEQ) ? kb + 128 : kb;
        {
            const ushort* kp0 = qkvb + (size_t)(nkb + krow) * RSTRIDE + DIM + kc8 * 8;
            kreg0 = *(const uint4*)kp0;
            kreg1 = *(const uint4*)(kp0 + (size_t)64 * RSTRIDE);
            const ushort* v0 =
                qkvb + (size_t)(nkb + 2 * vrp) * RSTRIDE + 2 * DIM + vc * 8;
            va = *(const uint4*)v0;
            vb = *(const uint4*)(v0 + RSTRIDE);
        }

        // S^T = K @ Q^T for 8 key tiles: lane l15 = q-row, reg r = key
        // (unscaled; scale folded into exp2)
        f32x4 s[8];
#pragma unroll
        for (int j = 0; j < 8; j++) {
            const ushort* kp = sK + (j * 16 + l15) * 64;
            bf16x8 bk0 = *(const bf16x8*)(kp + ((quad ^ sw) * 8));
            bf16x8 bk1 = *(const bf16x8*)(kp + (((4 | quad) ^ sw) * 8));
            f32x4 z = (f32x4){0.f, 0.f, 0.f, 0.f};
            __builtin_amdgcn_s_setprio(1);
            z = __builtin_amdgcn_mfma_f32_16x16x32_bf16(bk0, aq0, z, 0, 0, 0);
            z = __builtin_amdgcn_mfma_f32_16x16x32_bf16(bk1, aq1, z, 0, 0, 0);
            __builtin_amdgcn_s_setprio(0);
            s[j] = z;
        }

        // exp in-register, pack to bf16x4 A-fragments (k-order = reg order)
        s16x4 pa[8];
#pragma unroll
        for (int j = 0; j < 8; j++) {
            bf16x4 t;
#pragma unroll
            for (int r = 0; r < 4; r++)
                t[r] = (bf16_t)__builtin_amdgcn_exp2f(s[j][r] * c_exp);
            pa[j] = __builtin_bit_cast(s16x4, t);
        }

        // l_acc: row-sum of P via ones-MFMA (output row=q matches o layout)
        __builtin_amdgcn_s_setprio(1);
#pragma unroll
        for (int j = 0; j < 8; j++)
            l_acc = __builtin_amdgcn_mfma_f32_16x16x16bf16_1k(
                pa[j], vones, l_acc, 0, 0, 0);
        __builtin_amdgcn_s_setprio(0);

        // PV: o[jd] += P_tile_j @ V^T fragment, 16x16x16 per key tile
#pragma unroll
        for (int jd = 0; jd < 4; jd++) {
            const bf16_t* vp = (const bf16_t*)sVt + (jd * 16 + l15) * 128;
            __builtin_amdgcn_s_setprio(1);
#pragma unroll
            for (int j = 0; j < 8; j++) {
                int ch = 2 * j + qh;  // 16B chunk holding k = j*16 + quad*4
                bf16x4 bv = *(const bf16x4*)(vp + ((ch ^ sw) * 8 + q1 * 4));
                o[jd] = __builtin_amdgcn_mfma_f32_16x16x16bf16_1k(
                    pa[j], __builtin_bit_cast(s16x4, bv), o[jd], 0, 0, 0);
            }
            __builtin_amdgcn_s_setprio(0);
        }
        __syncthreads();  // all reads of sK/sVt done before next overwrite
    }

    // normalize, write attn [4096][1024] bf16
#pragma unroll
    for (int r = 0; r < 4; r++) {
        float inv = 1.f / l_acc[r];
        int qrow_i = q0 + w * 16 + quad * 4 + r;
#pragma unroll
        for (int j = 0; j < 4; j++) {
            out[(size_t)(b * SEQ + qrow_i) * DIM + h * 64 + j * 16 + l15] =
                f2bf(o[j][r] * inv);
        }
    }
}

extern "C" void kernel_launch(void* const* d_in, const int* in_sizes, int n_in,
                              void* d_out, int out_size, void* d_ws, size_t ws_size,
                              hipStream_t stream) {
    const float* x = (const float*)d_in[0];
    const float* w_qkv = (const float*)d_in[1];
    const float* w_o = (const float*)d_in[2];
    const float* b_o = (const float*)d_in[3];
    float* out = (float*)d_out;

    ushort* qkv = (ushort*)d_ws;                       // [4096][3072]
    ushort* attn = qkv + (size_t)ROWS * 3 * DIM;       // [4096][1024]
    ushort* xb = attn + (size_t)ROWS * DIM;            // [4096][1024]
    ushort* wqkvb = xb + (size_t)ROWS * DIM;           // [3072][1024]
    ushort* wob = wqkvb + (size_t)3 * DIM * DIM;       // [1024][1024]

    dim3 blk(256);
    // one fused conversion pass over x|w_qkv|w_o -> contiguous xb|wqkvb|wob
    cvt3_kernel<<<(ROWS * DIM + 3 * DIM * DIM + DIM * DIM) / 2048, blk, 0,
                  stream>>>(x, w_qkv, w_o, xb);

    gemm_bt_kernel<ushort, 128>
        <<<dim3(3 * DIM / 128, ROWS / 128), blk, 0, stream>>>(
            xb, wqkvb, nullptr, qkv, ROWS, 3 * DIM, DIM);
    flash_attn_kernel<<<dim3(SEQ / 128, BATCH * 16), dim3(512), 0, stream>>>(qkv, attn);
    gemm_bt_kernel<float, 64>
        <<<dim3(DIM / 64, ROWS / 128), blk, 0, stream>>>(
            attn, wob, b_o, out, ROWS, DIM, DIM);
}